// Round 1
// baseline (544.112 us; speedup 1.0000x reference)
//
#include <hip/hip_runtime.h>

// Problem constants (match reference)
#define B_ 64
#define C_ 256
#define HW_ 4096              // 64*64
#define HID_ 16
#define COND_ 32
#define RHID_ 64

// ---------------------------------------------------------------------------
// Kernel 1: global average pool.  One block per (b,c); 4096 contiguous floats
// = 1024 float4; 256 threads x 4 float4 each.  Fully coalesced.
// ---------------------------------------------------------------------------
__global__ __launch_bounds__(256) void gap_kernel(const float* __restrict__ x,
                                                  float* __restrict__ sem) {
    const int bc = blockIdx.x;                       // 0 .. B*C-1
    const float4* p = (const float4*)(x + (size_t)bc * HW_);
    const int t = threadIdx.x;                       // 0..255
    float s = 0.f;
#pragma unroll
    for (int i = 0; i < 4; ++i) {
        float4 v = p[t + 256 * i];
        s += (v.x + v.y) + (v.z + v.w);
    }
    // wave(64) butterfly reduce
#pragma unroll
    for (int off = 32; off > 0; off >>= 1) s += __shfl_down(s, off);
    __shared__ float ws[4];
    if ((t & 63) == 0) ws[t >> 6] = s;
    __syncthreads();
    if (t == 0) {
        float tot = (ws[0] + ws[1]) + (ws[2] + ws[3]);
        sem[bc] = tot * (1.0f / (float)HW_);
    }
}

// ---------------------------------------------------------------------------
// Kernel 2: all the tiny MLPs + exact top-k mask.  One block per batch sample,
// 256 threads (one per channel).  Everything fits in LDS; O(100K) FLOPs total.
// ---------------------------------------------------------------------------
__global__ __launch_bounds__(256) void head_kernel(
    const float* __restrict__ sem,      // [B,C]
    const float* __restrict__ base_cr,  // [1]
    const float* __restrict__ embed,    // [3,16]
    const float* __restrict__ snr_w1,   // [16,1]
    const float* __restrict__ snr_b1,   // [16]
    const float* __restrict__ snr_w2,   // [16,16]
    const float* __restrict__ snr_b2,   // [16]
    const float* __restrict__ sem_w,    // [16,256]
    const float* __restrict__ cond_w,   // [16,32]
    const float* __restrict__ out_w,    // [256,16]
    const float* __restrict__ r_w1,     // [64,288]
    const float* __restrict__ r_b1,     // [64]
    const float* __restrict__ r_w2,     // [64,64]
    const float* __restrict__ r_b2,     // [64]
    const float* __restrict__ r_w3,     // [1,64]
    const float* __restrict__ r_b3,     // [1]
    const int* __restrict__ channel_idx,
    const int* __restrict__ snr_db,
    float* __restrict__ mask,           // [B,C] out (0/1 floats)
    float* __restrict__ cr_out)         // [B] out
{
    const int b = blockIdx.x;
    const int t = threadIdx.x;

    __shared__ float hbuf[16];
    __shared__ float cond[COND_];
    __shared__ float semr[C_];
    __shared__ float fused[HID_];
    __shared__ float w[C_];
    __shared__ float r1[RHID_];
    __shared__ float r2[RHID_];
    __shared__ int   k_sh;

    const int   ci       = channel_idx[0];
    const float snr_norm = (float)snr_db[0] / 28.0f;

    semr[t] = sem[b * C_ + t];
    if (t < 16) hbuf[t] = fmaxf(snr_norm * snr_w1[t] + snr_b1[t], 0.f);
    __syncthreads();

    if (t < 16) {
        cond[t] = embed[ci * 16 + t];               // channel embedding half
    } else if (t < 32) {
        const int j = t - 16;                       // snr MLP half
        float acc = snr_b2[j];
        for (int kk = 0; kk < 16; ++kk) acc += hbuf[kk] * snr_w2[j * 16 + kk];
        cond[t] = fmaxf(acc, 0.f);
    }
    __syncthreads();

    // fused = relu(semantic @ sem_w.T + cond @ cond_w.T)   [16]
    if (t < HID_) {
        float acc = 0.f;
        for (int c = 0; c < C_; ++c)   acc += semr[c] * sem_w[t * C_ + c];
        for (int kk = 0; kk < COND_; ++kk) acc += cond[kk] * cond_w[t * COND_ + kk];
        fused[t] = fmaxf(acc, 0.f);
    }
    __syncthreads();

    // weights = sigmoid(fused @ out_w.T)   [256], one per thread
    {
        float acc = 0.f;
#pragma unroll
        for (int i = 0; i < HID_; ++i) acc += fused[i] * out_w[t * HID_ + i];
        w[t] = 1.f / (1.f + expf(-acc));
    }

    // rate controller
    if (t < RHID_) {
        float acc = r_b1[t];
        for (int c = 0; c < C_; ++c)    acc += semr[c] * r_w1[t * (C_ + COND_) + c];
        for (int kk = 0; kk < COND_; ++kk) acc += cond[kk] * r_w1[t * (C_ + COND_) + C_ + kk];
        r1[t] = fmaxf(acc, 0.f);
    }
    __syncthreads();                                // also publishes w[]
    if (t < RHID_) {
        float acc = r_b2[t];
        for (int i = 0; i < RHID_; ++i) acc += r1[i] * r_w2[t * RHID_ + i];
        r2[t] = fmaxf(acc, 0.f);
    }
    __syncthreads();
    if (t == 0) {
        float acc = r_b3[0];
        for (int i = 0; i < RHID_; ++i) acc += r2[i] * r_w3[i];
        const float raw = 1.f / (1.f + expf(-acc));
        const float dyn = 0.3f + 0.7f * raw;
        float cr = fminf(fmaxf(0.3f * base_cr[0] + 0.7f * dyn, 0.3f), 1.0f);
        cr_out[b] = cr;
        const float cr_safe = fminf(fmaxf(cr, 0.001f), 1.0f);
        int k = (int)rintf(cr_safe * (float)C_);    // rintf = half-to-even = jnp.round
        k = min(max(k, 1), C_);
        k_sh = k;
    }
    __syncthreads();

    // rank[t] = #{j : w[j] > w[t]}  +  #{j < t : w[j] == w[t]}  (stable argsort)
    const float wc = w[t];
    int cnt = 0;
    for (int j = 0; j < C_; ++j) {
        const float wj = w[j];
        cnt += (wj > wc) || (wj == wc && j < t);
    }
    mask[b * C_ + t] = (cnt < k_sh) ? 1.0f : 0.0f;
}

// ---------------------------------------------------------------------------
// Kernel 3: y = x * mask[b,c].  Grid-stride float4.  Mask index = (float4
// index) >> 10 since each (b,c) slab is 1024 float4.
// ---------------------------------------------------------------------------
__global__ __launch_bounds__(256) void apply_kernel(const float* __restrict__ x,
                                                    const float* __restrict__ mask,
                                                    float* __restrict__ y) {
    const size_t n4 = (size_t)B_ * C_ * HW_ / 4;    // 4,194,304 float4
    const size_t stride = (size_t)gridDim.x * blockDim.x;
    const float4* x4 = (const float4*)x;
    float4* y4 = (float4*)y;
    for (size_t i = (size_t)blockIdx.x * blockDim.x + threadIdx.x; i < n4; i += stride) {
        const float m = mask[i >> 10];
        float4 v = x4[i];
        v.x *= m; v.y *= m; v.z *= m; v.w *= m;
        y4[i] = v;
    }
}

// ---------------------------------------------------------------------------
extern "C" void kernel_launch(void* const* d_in, const int* in_sizes, int n_in,
                              void* d_out, int out_size, void* d_ws, size_t ws_size,
                              hipStream_t stream) {
    const float* x        = (const float*)d_in[0];
    const float* base_cr  = (const float*)d_in[1];
    const float* embed    = (const float*)d_in[2];
    const float* snr_w1   = (const float*)d_in[3];
    const float* snr_b1   = (const float*)d_in[4];
    const float* snr_w2   = (const float*)d_in[5];
    const float* snr_b2   = (const float*)d_in[6];
    const float* sem_w    = (const float*)d_in[7];
    const float* cond_w   = (const float*)d_in[8];
    const float* out_w    = (const float*)d_in[9];
    const float* r_w1     = (const float*)d_in[10];
    const float* r_b1     = (const float*)d_in[11];
    const float* r_w2     = (const float*)d_in[12];
    const float* r_b2     = (const float*)d_in[13];
    const float* r_w3     = (const float*)d_in[14];
    const float* r_b3     = (const float*)d_in[15];
    const int*   channel_idx = (const int*)d_in[16];
    const int*   snr_db      = (const int*)d_in[17];

    float* y      = (float*)d_out;
    float* cr_out = y + (size_t)B_ * C_ * HW_;      // cr_values appended after y

    float* sem  = (float*)d_ws;                     // [B*C] = 16384 floats
    float* mask = sem + B_ * C_;                    // [B*C] = 16384 floats

    gap_kernel<<<B_ * C_, 256, 0, stream>>>(x, sem);
    head_kernel<<<B_, 256, 0, stream>>>(sem, base_cr, embed, snr_w1, snr_b1,
                                        snr_w2, snr_b2, sem_w, cond_w, out_w,
                                        r_w1, r_b1, r_w2, r_b2, r_w3, r_b3,
                                        channel_idx, snr_db, mask, cr_out);
    apply_kernel<<<2048, 256, 0, stream>>>(x, mask, y);
}

// Round 5
// 531.749 us; speedup vs baseline: 1.0233x; 1.0233x over previous
//
#include <hip/hip_runtime.h>

// Problem constants (match reference)
#define B_ 64
#define C_ 256
#define HW_ 4096              // 64*64
#define HID_ 16
#define COND_ 32
#define RHID_ 64
#define NSLAB (B_ * C_)       // 16384 (b,c) slabs of 4096 floats

// Native clang vector type — __builtin_nontemporal_store rejects HIP's
// float4 (a HIP_vector_type class) but accepts a vector-of-float.
typedef float f32x4 __attribute__((ext_vector_type(4)));

// ---------------------------------------------------------------------------
// Kernel 1: global average pool.  One WAVE per (b,c) slab — no LDS, no
// __syncthreads, pure shuffle reduce.  2048 blocks x 4 waves = 8192 waves,
// grid-stride over 16384 slabs (2 slabs/wave).  Per slab: 1024 float4 read
// by 64 lanes = 16 coalesced float4 per lane.
// ---------------------------------------------------------------------------
__global__ __launch_bounds__(256) void gap_kernel(const float* __restrict__ x,
                                                  float* __restrict__ sem) {
    const int wave = (int)((blockIdx.x * 256u + threadIdx.x) >> 6);  // 0..8191
    const int lane = threadIdx.x & 63;
    for (int slab = wave; slab < NSLAB; slab += 8192) {
        const f32x4* p = (const f32x4*)(x + (size_t)slab * HW_);
        float s = 0.f;
#pragma unroll
        for (int i = 0; i < 16; ++i) {
            f32x4 v = p[lane + 64 * i];
            s += (v.x + v.y) + (v.z + v.w);
        }
#pragma unroll
        for (int off = 32; off > 0; off >>= 1) s += __shfl_down(s, off);
        if (lane == 0) sem[slab] = s * (1.0f / (float)HW_);
    }
}

// ---------------------------------------------------------------------------
// Kernel 2: all the tiny MLPs + exact top-k mask.  One block per batch sample,
// 256 threads (one per channel).  O(100K) FLOPs total — noise.
// ---------------------------------------------------------------------------
__global__ __launch_bounds__(256) void head_kernel(
    const float* __restrict__ sem,      // [B,C]
    const float* __restrict__ base_cr,  // [1]
    const float* __restrict__ embed,    // [3,16]
    const float* __restrict__ snr_w1,   // [16,1]
    const float* __restrict__ snr_b1,   // [16]
    const float* __restrict__ snr_w2,   // [16,16]
    const float* __restrict__ snr_b2,   // [16]
    const float* __restrict__ sem_w,    // [16,256]
    const float* __restrict__ cond_w,   // [16,32]
    const float* __restrict__ out_w,    // [256,16]
    const float* __restrict__ r_w1,     // [64,288]
    const float* __restrict__ r_b1,     // [64]
    const float* __restrict__ r_w2,     // [64,64]
    const float* __restrict__ r_b2,     // [64]
    const float* __restrict__ r_w3,     // [1,64]
    const float* __restrict__ r_b3,     // [1]
    const int* __restrict__ channel_idx,
    const int* __restrict__ snr_db,
    float* __restrict__ mask,           // [B,C] out (0/1 floats)
    float* __restrict__ cr_out)         // [B] out
{
    const int b = blockIdx.x;
    const int t = threadIdx.x;

    __shared__ float hbuf[16];
    __shared__ float cond[COND_];
    __shared__ float semr[C_];
    __shared__ float fused[HID_];
    __shared__ float w[C_];
    __shared__ float r1[RHID_];
    __shared__ float r2[RHID_];
    __shared__ int   k_sh;

    const int   ci       = channel_idx[0];
    const float snr_norm = (float)snr_db[0] / 28.0f;

    semr[t] = sem[b * C_ + t];
    if (t < 16) hbuf[t] = fmaxf(snr_norm * snr_w1[t] + snr_b1[t], 0.f);
    __syncthreads();

    if (t < 16) {
        cond[t] = embed[ci * 16 + t];               // channel embedding half
    } else if (t < 32) {
        const int j = t - 16;                       // snr MLP half
        float acc = snr_b2[j];
        for (int kk = 0; kk < 16; ++kk) acc += hbuf[kk] * snr_w2[j * 16 + kk];
        cond[t] = fmaxf(acc, 0.f);
    }
    __syncthreads();

    // fused = relu(semantic @ sem_w.T + cond @ cond_w.T)   [16]
    if (t < HID_) {
        float acc = 0.f;
        for (int c = 0; c < C_; ++c)   acc += semr[c] * sem_w[t * C_ + c];
        for (int kk = 0; kk < COND_; ++kk) acc += cond[kk] * cond_w[t * COND_ + kk];
        fused[t] = fmaxf(acc, 0.f);
    }
    __syncthreads();

    // weights = sigmoid(fused @ out_w.T)   [256], one per thread
    {
        float acc = 0.f;
#pragma unroll
        for (int i = 0; i < HID_; ++i) acc += fused[i] * out_w[t * HID_ + i];
        w[t] = 1.f / (1.f + expf(-acc));
    }

    // rate controller
    if (t < RHID_) {
        float acc = r_b1[t];
        for (int c = 0; c < C_; ++c)    acc += semr[c] * r_w1[t * (C_ + COND_) + c];
        for (int kk = 0; kk < COND_; ++kk) acc += cond[kk] * r_w1[t * (C_ + COND_) + C_ + kk];
        r1[t] = fmaxf(acc, 0.f);
    }
    __syncthreads();                                // also publishes w[]
    if (t < RHID_) {
        float acc = r_b2[t];
        for (int i = 0; i < RHID_; ++i) acc += r1[i] * r_w2[t * RHID_ + i];
        r2[t] = fmaxf(acc, 0.f);
    }
    __syncthreads();
    if (t == 0) {
        float acc = r_b3[0];
        for (int i = 0; i < RHID_; ++i) acc += r2[i] * r_w3[i];
        const float raw = 1.f / (1.f + expf(-acc));
        const float dyn = 0.3f + 0.7f * raw;
        float cr = fminf(fmaxf(0.3f * base_cr[0] + 0.7f * dyn, 0.3f), 1.0f);
        cr_out[b] = cr;
        const float cr_safe = fminf(fmaxf(cr, 0.001f), 1.0f);
        int k = (int)rintf(cr_safe * (float)C_);    // rintf = half-to-even = jnp.round
        k = min(max(k, 1), C_);
        k_sh = k;
    }
    __syncthreads();

    // rank[t] = #{j : w[j] > w[t]}  +  #{j < t : w[j] == w[t]}  (stable argsort)
    const float wc = w[t];
    int cnt = 0;
    for (int j = 0; j < C_; ++j) {
        const float wj = w[j];
        cnt += (wj > wc) || (wj == wc && j < t);
    }
    mask[b * C_ + t] = (cnt < k_sh) ? 1.0f : 0.0f;
}

// ---------------------------------------------------------------------------
// Kernel 3: y = x * mask[b,c].  Grid-stride float4, NONTEMPORAL stores for y
// so the write stream doesn't evict x from Infinity Cache — x was just
// streamed by gap_kernel and is exactly L3-sized, so the re-read can hit L3.
// ---------------------------------------------------------------------------
__global__ __launch_bounds__(256) void apply_kernel(const float* __restrict__ x,
                                                    const float* __restrict__ mask,
                                                    float* __restrict__ y) {
    const size_t n4 = (size_t)B_ * C_ * HW_ / 4;    // 4,194,304 float4
    const size_t stride = (size_t)gridDim.x * blockDim.x;
    const f32x4* x4 = (const f32x4*)x;
    f32x4* y4 = (f32x4*)y;
    for (size_t i = (size_t)blockIdx.x * blockDim.x + threadIdx.x; i < n4; i += stride) {
        const float m = mask[i >> 10];              // wave-uniform except at 16KiB seams
        f32x4 v = x4[i];
        v *= m;
        __builtin_nontemporal_store(v, y4 + i);
    }
}

// ---------------------------------------------------------------------------
extern "C" void kernel_launch(void* const* d_in, const int* in_sizes, int n_in,
                              void* d_out, int out_size, void* d_ws, size_t ws_size,
                              hipStream_t stream) {
    const float* x        = (const float*)d_in[0];
    const float* base_cr  = (const float*)d_in[1];
    const float* embed    = (const float*)d_in[2];
    const float* snr_w1   = (const float*)d_in[3];
    const float* snr_b1   = (const float*)d_in[4];
    const float* snr_w2   = (const float*)d_in[5];
    const float* snr_b2   = (const float*)d_in[6];
    const float* sem_w    = (const float*)d_in[7];
    const float* cond_w   = (const float*)d_in[8];
    const float* out_w    = (const float*)d_in[9];
    const float* r_w1     = (const float*)d_in[10];
    const float* r_b1     = (const float*)d_in[11];
    const float* r_w2     = (const float*)d_in[12];
    const float* r_b2     = (const float*)d_in[13];
    const float* r_w3     = (const float*)d_in[14];
    const float* r_b3     = (const float*)d_in[15];
    const int*   channel_idx = (const int*)d_in[16];
    const int*   snr_db      = (const int*)d_in[17];

    float* y      = (float*)d_out;
    float* cr_out = y + (size_t)B_ * C_ * HW_;      // cr_values appended after y

    float* sem  = (float*)d_ws;                     // [B*C] = 16384 floats
    float* mask = sem + B_ * C_;                    // [B*C] = 16384 floats

    gap_kernel<<<2048, 256, 0, stream>>>(x, sem);
    head_kernel<<<B_, 256, 0, stream>>>(sem, base_cr, embed, snr_w1, snr_b1,
                                        snr_w2, snr_b2, sem_w, cond_w, out_w,
                                        r_w1, r_b1, r_w2, r_b2, r_w3, r_b3,
                                        channel_idx, snr_db, mask, cr_out);
    apply_kernel<<<2048, 256, 0, stream>>>(x, mask, y);
}